// Round 2
// baseline (678.048 us; speedup 1.0000x reference)
//
#include <hip/hip_runtime.h>
#include <math.h>

#define SEQ 12
#define NBATCH 16384   // BC*NODES
#define FEAT 32
#define HID 64

// packed-weight layout offsets (floats) inside d_ws
#define WP_IH0 0
#define WP_HH0 6144
#define WP_IH1 18432
#define WP_HH1 30720
#define WP_TOTAL 43008
// z workspace starts after packed weights
#define Z_OFF WP_TOTAL

__device__ __forceinline__ float sigf(float x) { return 1.0f / (1.0f + __expf(-x)); }
__device__ __forceinline__ float tanh_fast(float x) { return 2.0f / (1.0f + __expf(-2.0f * x)) - 1.0f; }

#define DOT4(acc, A_, B_)                                   \
  acc = fmaf((A_).x, (B_).x, acc);                          \
  acc = fmaf((A_).y, (B_).y, acc);                          \
  acc = fmaf((A_).z, (B_).z, acc);                          \
  acc = fmaf((A_).w, (B_).w, acc);

// ---------------------------------------------------------------------------
// Pack weights transposed + k4-interleaved:
//   wp[((k>>2)*3 + g)*256 + j*4 + (k&3)] = W[(g*64+j)*K + k]
// so a thread owning unit j reads one float4 = W[g*64+j][4k..4k+3] per (k4,g).
// ---------------------------------------------------------------------------
__global__ void prep_kernel(const float* __restrict__ w_ih0, const float* __restrict__ w_hh0,
                            const float* __restrict__ w_ih1, const float* __restrict__ w_hh1,
                            float* __restrict__ wp)
{
  for (int i = blockIdx.x * blockDim.x + threadIdx.x; i < WP_TOTAL; i += gridDim.x * blockDim.x) {
    const float* src;
    int K, rel;
    if (i < WP_HH0)      { src = w_ih0; K = 32; rel = i; }
    else if (i < WP_IH1) { src = w_hh0; K = 64; rel = i - WP_HH0; }
    else if (i < WP_HH1) { src = w_ih1; K = 64; rel = i - WP_IH1; }
    else                 { src = w_hh1; K = 64; rel = i - WP_HH1; }
    int kr = rel & 3;
    int jj = (rel >> 2) & 63;
    int rest = rel >> 8;       // = k4*3 + g
    int g = rest % 3;
    int k4 = rest / 3;
    wp[i] = src[(g * 64 + jj) * K + k4 * 4 + kr];
  }
}

// ---------------------------------------------------------------------------
// Fused 2-layer GRU, 12 steps, 16 samples per block.
// thread (j = tid&63, sg = tid>>6) owns hidden unit j of samples sg*4..sg*4+3.
// Weights w_hh0, w_ih1, w_hh1 in LDS (144KB); w_ih0 via L1 (24KB working set).
// h-states in LDS (broadcast reads); x via per-lane loads.
// ---------------------------------------------------------------------------
__global__ __launch_bounds__(256, 1) void gru_kernel(
    const float* __restrict__ x,      // [12][16384][32]
    const float* __restrict__ wpack,  // packed weights
    const float* __restrict__ b_ih0, const float* __restrict__ b_hh0,
    const float* __restrict__ b_ih1, const float* __restrict__ b_hh1,
    float* __restrict__ zout)         // [2][16384][64]
{
  __shared__ float wlds[36864];       // whh0 | wih1 | whh1 (packed layout)
  __shared__ float h0s[16][64];
  __shared__ float h1s[16][64];
  const int tid = threadIdx.x;
  {
    const float4* src = (const float4*)(wpack + WP_HH0);
    float4* dst = (float4*)wlds;
    #pragma unroll 4
    for (int i = tid; i < 9216; i += 256) dst[i] = src[i];
  }
  const int j  = tid & 63;
  const int sg = __builtin_amdgcn_readfirstlane(tid >> 6);

  const float br0  = b_ih0[j]      + b_hh0[j];
  const float bz0  = b_ih0[64 + j] + b_hh0[64 + j];
  const float bni0 = b_ih0[128 + j];
  const float bnh0 = b_hh0[128 + j];
  const float br1  = b_ih1[j]      + b_hh1[j];
  const float bz1  = b_ih1[64 + j] + b_hh1[64 + j];
  const float bni1 = b_ih1[128 + j];
  const float bnh1 = b_hh1[128 + j];

  const int s0 = blockIdx.x * 16;
  float h0r[4] = {0.f, 0.f, 0.f, 0.f};
  float h1r[4] = {0.f, 0.f, 0.f, 0.f};
  #pragma unroll
  for (int ss = 0; ss < 4; ss++) { h0s[sg * 4 + ss][j] = 0.f; h1s[sg * 4 + ss][j] = 0.f; }
  __syncthreads();

  const float4* wih0g = (const float4*)(wpack + WP_IH0);
  const float4* whh0l = (const float4*)(wlds);
  const float4* wih1l = (const float4*)(wlds + 12288);
  const float4* whh1l = (const float4*)(wlds + 24576);

  for (int t = 0; t < SEQ; t++) {
    float ar[4], az[4], ani[4], anh[4];
    #pragma unroll
    for (int ss = 0; ss < 4; ss++) { ar[ss] = br0; az[ss] = bz0; ani[ss] = bni0; anh[ss] = bnh0; }

    // ---- layer 0: gi = x @ W_ih0^T (K=32), weights via L1 ----
    const float4* xr0 = (const float4*)(x + ((size_t)t * NBATCH + (s0 + sg * 4 + 0)) * FEAT);
    const float4* xr1 = (const float4*)(x + ((size_t)t * NBATCH + (s0 + sg * 4 + 1)) * FEAT);
    const float4* xr2 = (const float4*)(x + ((size_t)t * NBATCH + (s0 + sg * 4 + 2)) * FEAT);
    const float4* xr3 = (const float4*)(x + ((size_t)t * NBATCH + (s0 + sg * 4 + 3)) * FEAT);
    #pragma unroll
    for (int k4 = 0; k4 < 8; k4++) {
      float4 wr = wih0g[(k4 * 3 + 0) * 64 + j];
      float4 wz = wih0g[(k4 * 3 + 1) * 64 + j];
      float4 wn = wih0g[(k4 * 3 + 2) * 64 + j];
      float4 xv[4] = {xr0[k4], xr1[k4], xr2[k4], xr3[k4]};
      #pragma unroll
      for (int ss = 0; ss < 4; ss++) {
        DOT4(ar[ss],  wr, xv[ss]);
        DOT4(az[ss],  wz, xv[ss]);
        DOT4(ani[ss], wn, xv[ss]);
      }
    }
    // ---- layer 0: gh = h0 @ W_hh0^T (K=64), LDS ----
    #pragma unroll
    for (int k4 = 0; k4 < 16; k4++) {
      float4 wr = whh0l[(k4 * 3 + 0) * 64 + j];
      float4 wz = whh0l[(k4 * 3 + 1) * 64 + j];
      float4 wn = whh0l[(k4 * 3 + 2) * 64 + j];
      #pragma unroll
      for (int ss = 0; ss < 4; ss++) {
        float4 hv = *(const float4*)&h0s[sg * 4 + ss][k4 * 4];
        DOT4(ar[ss],  wr, hv);
        DOT4(az[ss],  wz, hv);
        DOT4(anh[ss], wn, hv);
      }
    }
    float h0n[4];
    #pragma unroll
    for (int ss = 0; ss < 4; ss++) {
      float rg = sigf(ar[ss]);
      float zg = sigf(az[ss]);
      float ng = tanh_fast(fmaf(rg, anh[ss], ani[ss]));
      h0n[ss] = fmaf(zg, h0r[ss] - ng, ng);   // (1-z)*n + z*h
    }
    __syncthreads();   // all gh0 reads done before overwrite
    #pragma unroll
    for (int ss = 0; ss < 4; ss++) { h0s[sg * 4 + ss][j] = h0n[ss]; h0r[ss] = h0n[ss]; }
    __syncthreads();   // h0 new visible to all

    // ---- layer 1 ----
    #pragma unroll
    for (int ss = 0; ss < 4; ss++) { ar[ss] = br1; az[ss] = bz1; ani[ss] = bni1; anh[ss] = bnh1; }
    #pragma unroll
    for (int k4 = 0; k4 < 16; k4++) {
      float4 wr = wih1l[(k4 * 3 + 0) * 64 + j];
      float4 wz = wih1l[(k4 * 3 + 1) * 64 + j];
      float4 wn = wih1l[(k4 * 3 + 2) * 64 + j];
      #pragma unroll
      for (int ss = 0; ss < 4; ss++) {
        float4 hv = *(const float4*)&h0s[sg * 4 + ss][k4 * 4];
        DOT4(ar[ss],  wr, hv);
        DOT4(az[ss],  wz, hv);
        DOT4(ani[ss], wn, hv);
      }
    }
    #pragma unroll
    for (int k4 = 0; k4 < 16; k4++) {
      float4 wr = whh1l[(k4 * 3 + 0) * 64 + j];
      float4 wz = whh1l[(k4 * 3 + 1) * 64 + j];
      float4 wn = whh1l[(k4 * 3 + 2) * 64 + j];
      #pragma unroll
      for (int ss = 0; ss < 4; ss++) {
        float4 hv = *(const float4*)&h1s[sg * 4 + ss][k4 * 4];
        DOT4(ar[ss],  wr, hv);
        DOT4(az[ss],  wz, hv);
        DOT4(anh[ss], wn, hv);
      }
    }
    float h1n[4];
    #pragma unroll
    for (int ss = 0; ss < 4; ss++) {
      float rg = sigf(ar[ss]);
      float zg = sigf(az[ss]);
      float ng = tanh_fast(fmaf(rg, anh[ss], ani[ss]));
      h1n[ss] = fmaf(zg, h1r[ss] - ng, ng);
    }
    __syncthreads();
    #pragma unroll
    for (int ss = 0; ss < 4; ss++) { h1s[sg * 4 + ss][j] = h1n[ss]; h1r[ss] = h1n[ss]; }
    __syncthreads();
  }

  #pragma unroll
  for (int ss = 0; ss < 4; ss++) {
    int s = s0 + sg * 4 + ss;
    zout[(size_t)s * 64 + j]            = h0r[ss];
    zout[(size_t)(NBATCH + s) * 64 + j] = h1r[ss];
  }
}

// ---------------------------------------------------------------------------
// GAT: flash-style fused attention per (layer*bc, 64-row tile).
// Block = 256 threads as 16x16 (r,c); each thread owns a 4x4 micro-tile.
// S = leaky_relu(Z Zt)*mask, masked_fill(==0, -1e16), online softmax, O = P V.
// ---------------------------------------------------------------------------
__global__ __launch_bounds__(256, 1) void gat_kernel(const float* __restrict__ z,
                                                     const int* __restrict__ mask,
                                                     float* __restrict__ out)
{
  __shared__ float Q [64][68];
  __shared__ float Kt[64][68];
  __shared__ float P [64][68];
  const int tid = threadIdx.x;
  const int rt = blockIdx.x & 15;    // row tile
  const int lb = blockIdx.x >> 4;    // l*16 + b  (0..31)
  const float* zb = z + (size_t)lb * 1024 * 64;
  const int n0 = rt * 64;

  // stage Q
  for (int i = tid; i < 1024; i += 256) {
    int row = i >> 4, c4 = i & 15;
    *(float4*)&Q[row][c4 * 4] = ((const float4*)(zb + (size_t)(n0 + row) * 64))[c4];
  }

  const int r = tid >> 4, c = tid & 15;
  float O[4][4];
  float Mr[4], Dr[4];
  #pragma unroll
  for (int a = 0; a < 4; a++) {
    Mr[a] = -INFINITY; Dr[a] = 0.f;
    #pragma unroll
    for (int b2 = 0; b2 < 4; b2++) O[a][b2] = 0.f;
  }

  for (int mt = 0; mt < 16; mt++) {
    __syncthreads();   // prev PV reads of Kt/P done (also covers initial Q staging)
    for (int i = tid; i < 1024; i += 256) {
      int row = i >> 4, c4 = i & 15;
      *(float4*)&Kt[row][c4 * 4] = ((const float4*)(zb + (size_t)(mt * 64 + row) * 64))[c4];
    }
    __syncthreads();

    // S = Q . Kt^T for the 4x4 micro-tile
    float S[4][4];
    #pragma unroll
    for (int a = 0; a < 4; a++)
      #pragma unroll
      for (int b2 = 0; b2 < 4; b2++) S[a][b2] = 0.f;
    #pragma unroll
    for (int k4 = 0; k4 < 16; k4++) {
      float4 q0 = *(const float4*)&Q[r * 4 + 0][k4 * 4];
      float4 q1 = *(const float4*)&Q[r * 4 + 1][k4 * 4];
      float4 q2 = *(const float4*)&Q[r * 4 + 2][k4 * 4];
      float4 q3 = *(const float4*)&Q[r * 4 + 3][k4 * 4];
      float4 k0 = *(const float4*)&Kt[c * 4 + 0][k4 * 4];
      float4 k1 = *(const float4*)&Kt[c * 4 + 1][k4 * 4];
      float4 k2 = *(const float4*)&Kt[c * 4 + 2][k4 * 4];
      float4 k3 = *(const float4*)&Kt[c * 4 + 3][k4 * 4];
      DOT4(S[0][0], q0, k0); DOT4(S[0][1], q0, k1); DOT4(S[0][2], q0, k2); DOT4(S[0][3], q0, k3);
      DOT4(S[1][0], q1, k0); DOT4(S[1][1], q1, k1); DOT4(S[1][2], q1, k2); DOT4(S[1][3], q1, k3);
      DOT4(S[2][0], q2, k0); DOT4(S[2][1], q2, k1); DOT4(S[2][2], q2, k2); DOT4(S[2][3], q2, k3);
      DOT4(S[3][0], q3, k0); DOT4(S[3][1], q3, k1); DOT4(S[3][2], q3, k2); DOT4(S[3][3], q3, k3);
    }

    // leaky_relu * mask, masked_fill(==0, -1e16)
    #pragma unroll
    for (int ri = 0; ri < 4; ri++) {
      const int4 mi = *(const int4*)(mask + (size_t)(n0 + r * 4 + ri) * 1024 + mt * 64 + c * 4);
      int mm[4] = {mi.x, mi.y, mi.z, mi.w};
      #pragma unroll
      for (int ci = 0; ci < 4; ci++) {
        float v = S[ri][ci];
        float lr = v > 0.f ? v : 0.1f * v;
        float a = mm[ci] ? lr : 0.f;
        S[ri][ci] = (a == 0.f) ? -1e16f : a;
      }
    }

    // online softmax update (rows live in 16-lane groups)
    #pragma unroll
    for (int ri = 0; ri < 4; ri++) {
      float m = fmaxf(fmaxf(S[ri][0], S[ri][1]), fmaxf(S[ri][2], S[ri][3]));
      #pragma unroll
      for (int w = 1; w < 16; w <<= 1) m = fmaxf(m, __shfl_xor(m, w, 16));
      float newM = fmaxf(Mr[ri], m);
      float sc = __expf(Mr[ri] - newM);   // first tile: exp(-inf)=0
      float ps = 0.f;
      #pragma unroll
      for (int ci = 0; ci < 4; ci++) {
        float p = __expf(S[ri][ci] - newM);
        S[ri][ci] = p;
        ps += p;
      }
      #pragma unroll
      for (int w = 1; w < 16; w <<= 1) ps += __shfl_xor(ps, w, 16);
      Dr[ri] = Dr[ri] * sc + ps;
      Mr[ri] = newM;
      #pragma unroll
      for (int ci = 0; ci < 4; ci++) O[ri][ci] *= sc;
      #pragma unroll
      for (int ci = 0; ci < 4; ci++) P[r * 4 + ri][c * 4 + ci] = S[ri][ci];
    }
    __syncthreads();

    // O += P * V  (V = Kt rows)
    #pragma unroll
    for (int m4 = 0; m4 < 16; m4++) {
      float4 v0 = *(const float4*)&Kt[m4 * 4 + 0][c * 4];
      float4 v1 = *(const float4*)&Kt[m4 * 4 + 1][c * 4];
      float4 v2 = *(const float4*)&Kt[m4 * 4 + 2][c * 4];
      float4 v3 = *(const float4*)&Kt[m4 * 4 + 3][c * 4];
      #pragma unroll
      for (int ri = 0; ri < 4; ri++) {
        float4 p4 = *(const float4*)&P[r * 4 + ri][m4 * 4];
        O[ri][0] = fmaf(p4.x, v0.x, O[ri][0]); O[ri][1] = fmaf(p4.x, v0.y, O[ri][1]);
        O[ri][2] = fmaf(p4.x, v0.z, O[ri][2]); O[ri][3] = fmaf(p4.x, v0.w, O[ri][3]);
        O[ri][0] = fmaf(p4.y, v1.x, O[ri][0]); O[ri][1] = fmaf(p4.y, v1.y, O[ri][1]);
        O[ri][2] = fmaf(p4.y, v1.z, O[ri][2]); O[ri][3] = fmaf(p4.y, v1.w, O[ri][3]);
        O[ri][0] = fmaf(p4.z, v2.x, O[ri][0]); O[ri][1] = fmaf(p4.z, v2.y, O[ri][1]);
        O[ri][2] = fmaf(p4.z, v2.z, O[ri][2]); O[ri][3] = fmaf(p4.z, v2.w, O[ri][3]);
        O[ri][0] = fmaf(p4.w, v3.x, O[ri][0]); O[ri][1] = fmaf(p4.w, v3.y, O[ri][1]);
        O[ri][2] = fmaf(p4.w, v3.z, O[ri][2]); O[ri][3] = fmaf(p4.w, v3.w, O[ri][3]);
      }
    }
  }

  // epilogue: divide by denom, store
  #pragma unroll
  for (int ri = 0; ri < 4; ri++) {
    float inv = 1.0f / Dr[ri];
    float4 o4 = make_float4(O[ri][0] * inv, O[ri][1] * inv, O[ri][2] * inv, O[ri][3] * inv);
    *(float4*)(out + ((size_t)lb * 1024 + n0 + r * 4 + ri) * 64 + c * 4) = o4;
  }
}

extern "C" void kernel_launch(void* const* d_in, const int* in_sizes, int n_in,
                              void* d_out, int out_size, void* d_ws, size_t ws_size,
                              hipStream_t stream) {
  const float* h     = (const float*)d_in[0];
  const int*   mask  = (const int*)d_in[1];
  const float* w_ih0 = (const float*)d_in[2];
  const float* w_hh0 = (const float*)d_in[3];
  const float* b_ih0 = (const float*)d_in[4];
  const float* b_hh0 = (const float*)d_in[5];
  const float* w_ih1 = (const float*)d_in[6];
  const float* w_hh1 = (const float*)d_in[7];
  const float* b_ih1 = (const float*)d_in[8];
  const float* b_hh1 = (const float*)d_in[9];
  float* out = (float*)d_out;
  float* ws  = (float*)d_ws;
  float* wpack = ws;
  float* zws   = ws + Z_OFF;

  prep_kernel<<<24, 256, 0, stream>>>(w_ih0, w_hh0, w_ih1, w_hh1, wpack);
  gru_kernel<<<1024, 256, 0, stream>>>(h, wpack, b_ih0, b_hh0, b_ih1, b_hh1, zws);
  gat_kernel<<<512, 256, 0, stream>>>(zws, mask, out);
}